// Round 14
// baseline (171.634 us; speedup 1.0000x reference)
//
#include <hip/hip_runtime.h>

// Problem constants
#define BSZ    8192
#define NWRD   4
#define SEQL   16
#define HDIM   128
#define VOCAB  64
#define NSEQ   (BSZ * NWRD)    // 32768
#define WGSEQ  32              // sequences per workgroup
#define UPB    80              // units per length-bin (80*32=2560 slots)
#define BINCAP (UPB * WGSEQ)   // 2560
#define NBLK   512             // persistent blocks
#define RSTR   136             // epilogue reps row stride (kills 8-way conflicts)

#define AS1 __attribute__((address_space(1)))
#define AS3 __attribute__((address_space(3)))

typedef float    f32x4  __attribute__((ext_vector_type(4)));
typedef __bf16   bf16x8 __attribute__((ext_vector_type(8)));
typedef _Float16 f16x4  __attribute__((ext_vector_type(4)));
typedef int      i32x4  __attribute__((ext_vector_type(4)));

__device__ __forceinline__ unsigned short f2bf(float f) {
    unsigned int u = __builtin_bit_cast(unsigned int, f);
    return (unsigned short)((u + 0x7fff + ((u >> 16) & 1)) >> 16);  // RNE
}
__device__ __forceinline__ float sigm(float x) {
    return __builtin_amdgcn_rcpf(1.f + __builtin_amdgcn_exp2f(x * -1.44269504f));
}

// ---------------------------------------------------------------------------
// Fused prep (512 blocks), v14 layouts for the 16x16x32 decomposition:
//  blocks 0..127  : P table f16: row v (1KB), quad qidx=g*32+(j>>2), elem j&3;
//                   half-index F = v*512 + ((qidx*4 + (j&3)) ^ ((v&7)<<3))
//                   (byte-XOR (v&7)<<4 for LDS bank spread on b64 reads).
//  blocks 128..383: WA = W_hh bf16 A-frags for 16x16x32:
//                   n = g*128 + wv*16 + (lane&15), k = kc*32 + (lane>>4)*8 + jj
//                   WA[(((wv*4+g)*4+kc)*64+lane)*8+jj], wv in [0,8).
//  blocks 384..511: binned scatter: bin=16-len, cursor in gh[b] (unchanged).
// ---------------------------------------------------------------------------
__global__ void prep4(const float* __restrict__ emb, const float* __restrict__ W_ih,
                      const float* __restrict__ b_ih, const float* __restrict__ b_hh,
                      const float* __restrict__ W_hh, const int* __restrict__ lengths,
                      unsigned short* __restrict__ P2H, unsigned short* __restrict__ WA,
                      int* __restrict__ perm, int* __restrict__ gh)
{
    __shared__ int lh[16], gbase[16];
    const int blk = blockIdx.x, tid = threadIdx.x;

    if (blk < 128) {
        int idx = blk * 256 + tid;                 // 32768 = v*512 + g*128 + j
        int v = idx >> 9, g = (idx >> 7) & 3, j = idx & 127;
        int n = g * 128 + j;
        const f32x4* er = (const f32x4*)(emb  + v * 128);
        const f32x4* wr = (const f32x4*)(W_ih + n * 128);
        f32x4 s4 = er[0] * wr[0];
#pragma unroll
        for (int e = 1; e < 32; ++e) s4 += er[e] * wr[e];
        float s = s4.x + s4.y + s4.z + s4.w + b_ih[n] + b_hh[n];
        int qidx = g * 32 + (j >> 2);
        int F = v * 512 + (((qidx << 2) + (j & 3)) ^ ((v & 7) << 3));
        P2H[F] = __builtin_bit_cast(unsigned short, (_Float16)s);
    } else if (blk < 384) {
        int idx = (blk - 128) * 256 + tid;         // 65536
        int jj = idx & 7, lane = (idx >> 3) & 63, kc = (idx >> 9) & 3, tt = idx >> 11;
        int wv = tt >> 2, g = tt & 3;              // tt in [0,32)
        int n = g * 128 + wv * 16 + (lane & 15);
        int k = kc * 32 + ((lane >> 4) & 3) * 8 + jj;
        WA[idx] = f2bf(W_hh[n * 128 + k]);
    } else {
        if (tid < 16) lh[tid] = 0;
        __syncthreads();
        int i = (blk - 384) * 256 + tid;           // 32768 sequences
        int b = 16 - lengths[i];                   // descending-length bins
        int rank = atomicAdd(&lh[b], 1);
        __syncthreads();
        if (tid < 16) gbase[tid] = atomicAdd(&gh[tid], lh[tid]);
        __syncthreads();
        perm[b * BINCAP + gbase[b] + rank] = i;
    }
}

// ---------------------------------------------------------------------------
// LSTM v14b: 16x16x32 MFMA decomposition for occupancy.
// 512-thread blocks (8 waves); wave wv owns j-slice [wv*16, wv*16+16) of all
// 4 gates; each lane serves 2 seqs (lane&15 and +16, the two 16-seq tiles).
// Per-wave regs: afr 4gx4kc = 64, acc 4gx2st(f32x4) = 32, cq 8, words 8
// -> target <=128 total => 4 waves/SIMD (2 blocks/CU, LDS 81920 exact; 2x
// R12's occupancy). v14b FIX: __launch_bounds__(512,4) — 2nd arg is waves
// per EU, so (512,2) requested only 1 block/CU and uncapped registers;
// (512,4) = 4 waves/SIMD = 2 co-resident 8-wave blocks + 128-reg cap.
// Fragment maps (HW-validated conventions):
//   A/B: m,n = lane&15, k = (lane>>4)*8+jj;  C/D: col=lane&15,
//   row = (lane>>4)*4 + r  => lane's j-quad = wv*16 + (lane>>4)*4.
// Everything else (persistent LPT ticket, LDS ptab, 1 barrier/step,
// hw-exp2 single-rcp gates) is the verified R6/R12 structure.
// ---------------------------------------------------------------------------
__global__ __launch_bounds__(512, 4) void lstm4(
    const int* __restrict__ word_ids, const int* __restrict__ perm,
    int* __restrict__ gh, const unsigned short* __restrict__ P2H,
    const unsigned short* __restrict__ WA, float* __restrict__ c_out)
{
    __shared__ __align__(16) unsigned short ptab[VOCAB * 512];     // 64 KB
    __shared__ __align__(16) unsigned short hbuf[2][WGSEQ * 128];  // 16 KB

    const int tid  = threadIdx.x;
    const int wv   = tid >> 6;        // 0..7
    const int lane = tid & 63;
    const int l15  = lane & 15;       // seq-in-tile (MFMA n / C col)
    const int hi   = (lane >> 4) & 3; // k-group / j-quad selector

    // stage the whole P table into LDS (8 waves x 8 KB, async, once/block)
    {
        const char* src = (const char*)P2H;
        char*       dst = (char*)ptab;
#pragma unroll
        for (int r = 0; r < 8; ++r) {
            const int off = (wv * 8 + r) * 1024;    // wave-uniform dest base
            __builtin_amdgcn_global_load_lds(
                (const AS1 unsigned int*)(src + off + lane * 16),
                (AS3 unsigned int*)(dst + off), 16, 0, 0);
        }
    }

    // A fragments: W_hh slice for this wave's 16-j cols (64 VGPR)
    bf16x8 afr[4][4];
#pragma unroll
    for (int g = 0; g < 4; ++g)
#pragma unroll
        for (int kc = 0; kc < 4; ++kc)
            afr[g][kc] = *(const bf16x8*)(WA + (((wv * 4 + g) * 4 + kc) * 64 + lane) * 8);

    // bin populations -> SGPRs (uniform) + total unit count
    int ghs[16];
#pragma unroll
    for (int i = 0; i < 16; ++i)
        ghs[i] = __builtin_amdgcn_readfirstlane(gh[i]);
    int tot = 0;
#pragma unroll
    for (int i = 0; i < 16; ++i) tot += (ghs[i] + 31) >> 5;

    const unsigned xv  = (unsigned)((l15 & 7) << 4);   // seq-row XOR (both tiles)
    const int      jql = wv * 16 + hi * 4;             // lane's j-quad base
    const unsigned pqb = (unsigned)((jql >> 2) * 8);   // ptab quad byte (g adds g*256)
    int* const tick_p = (int*)&hbuf[0][0];             // ticket broadcast slot

    for (;;) {
        __syncthreads();               // prev unit's hbuf reads done
                                       // (iter 0: drains ptab staging)
        if (tid == 0) *tick_p = atomicAdd(gh + 16, 1);
        __syncthreads();               // ticket visible to all waves
        const int k = *tick_p;
        if (k >= tot) break;

        // map ticket -> (bin, widx): longest-first (b ascending), scalar
        int rem = k, bsel = 0, found = 0;
#pragma unroll
        for (int b2 = 0; b2 < 16; ++b2) {
            int nb = (ghs[b2] + 31) >> 5;
            if (!found) {
                if (rem < nb) { bsel = b2; found = 1; }
                else rem -= nb;
            }
        }
        const int widx = rem;
        const int cnt  = ghs[bsel];
        const int ml   = 16 - bsel;    // uniform trip count (>=1)

        // 2 seqs per lane: slot0 = l15 (tile 0), slot1 = 16+l15 (tile 1)
        const int slot0 = widx * WGSEQ + l15;
        const int slot1 = slot0 + 16;
        const int live0 = slot0 < cnt;
        const int live1 = slot1 < cnt;
        const int sid0  = live0 ? perm[bsel * BINCAP + slot0] : 0;
        const int sid1  = live1 ? perm[bsel * BINCAP + slot1] : 0;

        unsigned long long u0a, u1a, u0b, u1b;
        {
            const i32x4* wp = (const i32x4*)(word_ids + sid0 * SEQL);
            i32x4 a = wp[0], b4 = wp[1], c4 = wp[2], d4 = wp[3];
            u0a = ((unsigned long long)(unsigned)(b4.x | (b4.y << 8) | (b4.z << 16) | (b4.w << 24)) << 32)
                |  (unsigned)(a.x  | (a.y  << 8) | (a.z  << 16) | (a.w  << 24));
            u1a = ((unsigned long long)(unsigned)(d4.x | (d4.y << 8) | (d4.z << 16) | (d4.w << 24)) << 32)
                |  (unsigned)(c4.x | (c4.y << 8) | (c4.z << 16) | (c4.w << 24));
        }
        {
            const i32x4* wp = (const i32x4*)(word_ids + sid1 * SEQL);
            i32x4 a = wp[0], b4 = wp[1], c4 = wp[2], d4 = wp[3];
            u0b = ((unsigned long long)(unsigned)(b4.x | (b4.y << 8) | (b4.z << 16) | (b4.w << 24)) << 32)
                |  (unsigned)(a.x  | (a.y  << 8) | (a.z  << 16) | (a.w  << 24));
            u1b = ((unsigned long long)(unsigned)(d4.x | (d4.y << 8) | (d4.z << 16) | (d4.w << 24)) << 32)
                |  (unsigned)(c4.x | (c4.y << 8) | (c4.z << 16) | (c4.w << 24));
        }

        f32x4 cq0 = {0,0,0,0}, cq1 = {0,0,0,0};

#pragma unroll 1
        for (int t = 0; t < ml; ++t) {
            const int w0 = (int)(u0a & 63);
            u0a = (u0a >> 8) | (u1a << 56); u1a >>= 8;
            const int w1 = (int)(u0b & 63);
            u0b = (u0b >> 8) | (u1b << 56); u1b >>= 8;

            // acc init = gate pre-activations P[w] (b64 reads, 4 f16 each)
            f32x4 acc[4][2];   // [gate][seqtile], all indices compile-time
            {
                const char*    r0  = (const char*)ptab + (w0 << 10);
                const unsigned wx0 = (unsigned)((w0 & 7) << 4);
                const char*    r1  = (const char*)ptab + (w1 << 10);
                const unsigned wx1 = (unsigned)((w1 & 7) << 4);
#pragma unroll
                for (int g = 0; g < 4; ++g) {
                    const unsigned bo = (unsigned)(g * 256) + pqb;
                    f16x4 p0 = *(const f16x4*)(r0 + (bo ^ wx0));
                    f16x4 p1 = *(const f16x4*)(r1 + (bo ^ wx1));
#pragma unroll
                    for (int d = 0; d < 4; ++d) {
                        acc[g][0][d] = (float)p0[d];
                        acc[g][1][d] = (float)p1[d];
                    }
                }
            }

            if (t > 0) {   // recurrent GEMM (t=0 has h=0)
                const char* hr = (const char*)hbuf[t & 1];
                const int row0 = l15 * 256, row1 = row0 + 16 * 256;
#pragma unroll
                for (int kc = 0; kc < 4; ++kc) {
                    const unsigned ko = (unsigned)(kc * 64 + hi * 16);
                    bf16x8 b0 = *(const bf16x8*)(hr + row0 + (ko ^ xv));
                    bf16x8 b1 = *(const bf16x8*)(hr + row1 + (ko ^ xv));
#pragma unroll
                    for (int g = 0; g < 4; ++g) {
                        acc[g][0] = __builtin_amdgcn_mfma_f32_16x16x32_bf16(
                            afr[g][kc], b0, acc[g][0], 0, 0, 0);
                        acc[g][1] = __builtin_amdgcn_mfma_f32_16x16x32_bf16(
                            afr[g][kc], b1, acc[g][1], 0, 0, 0);
                    }
                }
            }

            const int wr = (t < ml - 1);
            char* hw = (char*)hbuf[(t + 1) & 1];
#pragma unroll
            for (int st = 0; st < 2; ++st) {
                float hv4[4];
#pragma unroll
                for (int d = 0; d < 4; ++d) {
                    float cprev = st ? cq1[d] : cq0[d];
                    // single-rcp cell update (exact algebra):
                    // cn = (c*(1+ei)(1+eg) + (eg-1)(1+ef)) / ((1+ef)(1+ei)(1+eg))
                    float ei = __builtin_amdgcn_exp2f(acc[0][st][d] * -1.44269504f);
                    float ef = __builtin_amdgcn_exp2f(acc[1][st][d] * -1.44269504f);
                    float eg = __builtin_amdgcn_exp2f(acc[2][st][d] *  2.88539008f);
                    float ai = 1.f + ei, af = 1.f + ef, ag = 1.f + eg;
                    float t1 = ai * ag;
                    float R  = __builtin_amdgcn_rcpf(t1 * af);
                    float cn = __builtin_fmaf(cprev, t1, (eg - 1.f) * af) * R;
                    if (st) cq1[d] = cn; else cq0[d] = cn;
                    if (wr) {
                        // h = sig(o)*tanh(cn) = (ec-1)/((1+eo)(1+ec))
                        float eo = __builtin_amdgcn_exp2f(acc[3][st][d] * -1.44269504f);
                        float ec = __builtin_amdgcn_exp2f(cn * 2.88539008f);
                        hv4[d] = (ec - 1.f) *
                                 __builtin_amdgcn_rcpf((1.f + eo) * (1.f + ec));
                    }
                }
                if (wr) {
                    unsigned int plo_, phi_;
                    asm("v_cvt_pk_bf16_f32 %0, %1, %2"
                        : "=v"(plo_) : "v"(hv4[0]), "v"(hv4[1]));
                    asm("v_cvt_pk_bf16_f32 %0, %1, %2"
                        : "=v"(phi_) : "v"(hv4[2]), "v"(hv4[3]));
                    unsigned long long pu_ =
                        ((unsigned long long)phi_ << 32) | plo_;
                    *(unsigned long long*)(hw + (st * 16 + l15) * 256 +
                        (((unsigned)(jql * 2)) ^ xv)) = pu_;
                }
            }
            if (wr) __syncthreads();   // h(t+1) visible; single barrier/step
        }

        // final cell state -> original seq order (dwordx4 stores, one quad/seq)
        if (live0) *(f32x4*)(c_out + sid0 * HDIM + jql) = cq0;
        if (live1) *(f32x4*)(c_out + sid1 * HDIM + jql) = cq1;
    }
}

// ---------------------------------------------------------------------------
// Per-batch epilogue: gram -> cosine -> conv1 -> conv2 -> scorer -> sigmoid.
// reps row stride 136 f32 -> gram-dot rows on bank offsets {0,8,16,24}
// (verified -4us on residue, R9).
// ---------------------------------------------------------------------------
__global__ __launch_bounds__(256) void epilogue(
    const float* __restrict__ c_ws,
    const float* __restrict__ conv1_w, const float* __restrict__ conv1_b,
    const float* __restrict__ conv2_w, const float* __restrict__ conv2_b,
    const float* __restrict__ scorer_w, const float* __restrict__ scorer_b,
    float* __restrict__ out)
{
    __shared__ __align__(16) float reps[8 * NWRD * RSTR];   // 17.4 KB
    __shared__ float gram_s[8 * 16];

    const int tid = threadIdx.x;
    const int b0  = blockIdx.x * 8;

    for (int i = tid; i < 8 * NWRD * HDIM; i += 256)
        reps[(i >> 7) * RSTR + (i & 127)] = c_ws[b0 * NWRD * HDIM + i];
    __syncthreads();

    const int bt  = tid >> 5;   // 0..7
    const int sub = tid & 31;

    float dval = 0.f;
    if (sub < 16) {
        int i = sub >> 2, j = sub & 3;
        const f32x4* ci = (const f32x4*)(reps + (bt * 4 + i) * RSTR);
        const f32x4* cj = (const f32x4*)(reps + (bt * 4 + j) * RSTR);
        f32x4 s4 = {0.f, 0.f, 0.f, 0.f};
        for (int k = 0; k < HDIM / 4; ++k) s4 += ci[k] * cj[k];
        dval = s4.x + s4.y + s4.z + s4.w;
        gram_s[bt * 16 + sub] = dval;
    }
    __syncthreads();
    float cosv = 0.f;
    if (sub < 16) {
        int i = sub >> 2, j = sub & 3;
        float di = gram_s[bt * 16 + i * 4 + i];
        float dj = gram_s[bt * 16 + j * 4 + j];
        cosv = __fdividef(dval, sqrtf(di * dj));
    }
    __syncthreads();
    if (sub < 16) gram_s[bt * 16 + sub] = cosv;
    __syncthreads();

    if (sub == 0) {
        float img[4][4];
#pragma unroll
        for (int i = 0; i < 4; ++i)
#pragma unroll
            for (int j = 0; j < 4; ++j) img[i][j] = gram_s[bt * 16 + i * 4 + j];

        float o1[4][3][3];
#pragma unroll
        for (int ch = 0; ch < 4; ++ch) {
            float w00 = conv1_w[ch*4+0], w01 = conv1_w[ch*4+1];
            float w10 = conv1_w[ch*4+2], w11 = conv1_w[ch*4+3];
            float bb  = conv1_b[ch];
#pragma unroll
            for (int y = 0; y < 3; ++y)
#pragma unroll
                for (int x = 0; x < 3; ++x) {
                    float s = bb + w00*img[y][x]   + w01*img[y][x+1]
                                 + w10*img[y+1][x] + w11*img[y+1][x+1];
                    o1[ch][y][x] = s > 0.f ? s : 0.f;
                }
        }
        float sc = scorer_b[0];
#pragma unroll
        for (int oc = 0; oc < 8; ++oc) {
            float bb = conv2_b[oc];
#pragma unroll
            for (int y = 0; y < 2; ++y)
#pragma unroll
                for (int x = 0; x < 2; ++x) {
                    float s = bb;
#pragma unroll
                    for (int ic = 0; ic < 4; ++ic) {
                        const float* w = conv2_w + oc * 16 + ic * 4;
                        s += w[0]*o1[ic][y][x]   + w[1]*o1[ic][y][x+1]
                           + w[2]*o1[ic][y+1][x] + w[3]*o1[ic][y+1][x+1];
                    }
                    float rl = s > 0.f ? s : 0.f;
                    sc += rl * scorer_w[oc * 4 + y * 2 + x];
                }
        }
        out[blockIdx.x * 8 + bt] = sigm(sc);
    }
}

extern "C" void kernel_launch(void* const* d_in, const int* in_sizes, int n_in,
                              void* d_out, int out_size, void* d_ws, size_t ws_size,
                              hipStream_t stream)
{
    const int*   word_ids = (const int*)d_in[0];
    const int*   lengths  = (const int*)d_in[1];
    const float* emb      = (const float*)d_in[2];
    const float* W_ih     = (const float*)d_in[3];
    const float* W_hh     = (const float*)d_in[4];
    const float* b_ih     = (const float*)d_in[5];
    const float* b_hh     = (const float*)d_in[6];
    const float* conv1_w  = (const float*)d_in[7];
    const float* conv1_b  = (const float*)d_in[8];
    const float* conv2_w  = (const float*)d_in[9];
    const float* conv2_b  = (const float*)d_in[10];
    const float* scorer_w = (const float*)d_in[11];
    const float* scorer_b = (const float*)d_in[12];
    float* out = (float*)d_out;

    // workspace layout
    char* ws = (char*)d_ws;
    unsigned short* P2H  = (unsigned short*)(ws + 0);         // 64 KB (f16 table)
    unsigned short* WA   = (unsigned short*)(ws + (128<<10)); // 128 KB
    int*            perm = (int*)(ws + (256<<10));            // 16*2560*4 = 160 KB
    int*            gh   = (int*)(ws + (416<<10));            // 16 cursors + ticket
    float*          c_ws = (float*)(ws + (512<<10));          // 16 MB

    hipMemsetAsync(gh, 0, 17 * sizeof(int), stream);
    prep4   <<<512,  256, 0, stream>>>(emb, W_ih, b_ih, b_hh, W_hh, lengths,
                                       P2H, WA, perm, gh);
    lstm4   <<<NBLK, 512, 0, stream>>>(word_ids, perm, gh, P2H, WA, c_ws);
    epilogue<<<BSZ / 8, 256, 0, stream>>>(c_ws, conv1_w, conv1_b, conv2_w, conv2_b,
                                          scorer_w, scorer_b, out);
}

// Round 15
// 164.561 us; speedup vs baseline: 1.0430x; 1.0430x over previous
//
#include <hip/hip_runtime.h>

// Problem constants
#define BSZ    8192
#define NWRD   4
#define SEQL   16
#define HDIM   128
#define VOCAB  64
#define NSEQ   (BSZ * NWRD)    // 32768
#define WGSEQ  32              // sequences per workgroup
#define UPB    80              // units per length-bin (80*32=2560 slots)
#define BINCAP (UPB * WGSEQ)   // 2560
#define NBLK   512             // persistent blocks = 2/CU, all co-resident
#define RSTR   136             // epilogue reps row stride (kills 8-way conflicts)

#define AS1 __attribute__((address_space(1)))
#define AS3 __attribute__((address_space(3)))

typedef float    f32x4  __attribute__((ext_vector_type(4)));
typedef float    f32x16 __attribute__((ext_vector_type(16)));
typedef __bf16   bf16x8 __attribute__((ext_vector_type(8)));
typedef _Float16 f16x8  __attribute__((ext_vector_type(8)));
typedef int      i32x4  __attribute__((ext_vector_type(4)));

union AccU { f32x16 v; f32x4 q[4]; float f[16]; };

__device__ __forceinline__ unsigned short f2bf(float f) {
    unsigned int u = __builtin_bit_cast(unsigned int, f);
    return (unsigned short)((u + 0x7fff + ((u >> 16) & 1)) >> 16);  // RNE
}
__device__ __forceinline__ float sigm(float x) {
    return __builtin_amdgcn_rcpf(1.f + __builtin_amdgcn_exp2f(x * -1.44269504f));
}

// ---------------------------------------------------------------------------
// Fused prep (512 blocks):
//  blocks 0..127  : P table in f16, LSTM-fragment layout + per-row chunk
//                   XOR (chunk ^= v&7) for LDS bank spread.
//  blocks 128..383: WA = W_hh bf16, A-fragment order (HW-validated).
//  blocks 384..511: binned scatter: bin=16-len, cursor in gh[b].
// ---------------------------------------------------------------------------
__global__ void prep4(const float* __restrict__ emb, const float* __restrict__ W_ih,
                      const float* __restrict__ b_ih, const float* __restrict__ b_hh,
                      const float* __restrict__ W_hh, const int* __restrict__ lengths,
                      unsigned short* __restrict__ P2H, unsigned short* __restrict__ WA,
                      int* __restrict__ perm, int* __restrict__ gh)
{
    __shared__ int lh[16], gbase[16];
    const int blk = blockIdx.x, tid = threadIdx.x;

    if (blk < 128) {
        int idx = blk * 256 + tid;                 // 32768 = v*512 + g*128 + j
        int v = idx >> 9, g = (idx >> 7) & 3, j = idx & 127;
        int n = g * 128 + j;
        const f32x4* er = (const f32x4*)(emb  + v * 128);
        const f32x4* wr = (const f32x4*)(W_ih + n * 128);
        f32x4 s4 = er[0] * wr[0];
#pragma unroll
        for (int e = 1; e < 32; ++e) s4 += er[e] * wr[e];
        float s = s4.x + s4.y + s4.z + s4.w + b_ih[n] + b_hh[n];
        // scatter into LSTM fragment layout (f16)
        int wv = j >> 5, jr = j & 31;
        int d = jr & 3, hl = (jr >> 2) & 1, q = jr >> 3;
        int cc = g * 16 + wv * 4 + hl * 2 + (q >> 1);
        int F  = v * 512 + ((cc ^ (v & 7)) << 3) + (q & 1) * 4 + d;
        P2H[F] = __builtin_bit_cast(unsigned short, (_Float16)s);
    } else if (blk < 384) {
        int idx = (blk - 128) * 256 + tid;         // 65536
        int jj = idx & 7, lane = (idx >> 3) & 63, kc = (idx >> 9) & 7, tt = idx >> 12;
        int wv = tt >> 2, g = tt & 3;
        int n = g * 128 + wv * 32 + (lane & 31);
        int k = kc * 16 + (lane >> 5) * 8 + jj;
        WA[idx] = f2bf(W_hh[n * 128 + k]);
    } else {
        if (tid < 16) lh[tid] = 0;
        __syncthreads();
        int i = (blk - 384) * 256 + tid;           // 32768 sequences
        int b = 16 - lengths[i];                   // descending-length bins
        int rank = atomicAdd(&lh[b], 1);
        __syncthreads();
        if (tid < 16) gbase[tid] = atomicAdd(&gh[tid], lh[tid]);
        __syncthreads();
        perm[b * BINCAP + gbase[b] + rank] = i;
    }
}

// ---------------------------------------------------------------------------
// LSTM, transposed GEMM: gates^T = W_hh(A, regs) x h^T(B, LDS).
// v15 = R12/R6 body EXACTLY (verified 69.9-70.1us). Closed search branches,
// each with a measured, understood failure mechanism:
//  - pexp2 (R9): no trans/main dual-issue -> net issue work, +11us
//  - s_setprio (R10): codegen perturbation -> scratch traffic, +12us
//  - identity-MFMA (R4): +56 regs -> spills
//  - 16x16x32 re-decomposition (R14): occupancy 2x but perf -5.4us ->
//    TLP not binding; spills at the 64-reg squeeze (WRITE +14MB)
//  - fusion via grid barrier / fences (R7/R8/R11): cross-XCD coherence ops
//    invalidate whole-XCD L2; kernel-boundary flush is cheaper.
// Structure: persistent LPT ticket (broadcast through hbuf[0][0]; LDS exactly
// 81920 B -> 2 blocks/CU), LDS-resident f16 P-table, reg-resident W_hh frags,
// 1 barrier/step, hw-exp2 single-rcp gates, packed h-writes.
// ---------------------------------------------------------------------------
__global__ __launch_bounds__(256, 2) void lstm4(
    const int* __restrict__ word_ids, const int* __restrict__ perm,
    int* __restrict__ gh, const unsigned short* __restrict__ P2H,
    const unsigned short* __restrict__ WA, float* __restrict__ c_out)
{
    __shared__ __align__(16) unsigned short ptab[VOCAB * 512];     // 64 KB
    __shared__ __align__(16) unsigned short hbuf[2][WGSEQ * 128];  // 16 KB

    const int tid    = threadIdx.x;
    const int wv     = tid >> 6;
    const int lane   = tid & 63;
    const int lane31 = lane & 31;
    const int hl     = lane >> 5;

    // stage the whole P table into LDS (linear copy, async; once per block)
    {
        const char* src = (const char*)P2H;
        char*       dst = (char*)ptab;
#pragma unroll
        for (int r = 0; r < 16; ++r) {
            const int off = r * 4096 + wv * 1024;   // wave-uniform dest base
            __builtin_amdgcn_global_load_lds(
                (const AS1 unsigned int*)(src + off + lane * 16),
                (AS3 unsigned int*)(dst + off), 16, 0, 0);
        }
    }

    // A fragments: W_hh, persistent in registers (once per block)
    bf16x8 afr[4][8];
#pragma unroll
    for (int g = 0; g < 4; ++g)
#pragma unroll
        for (int kc = 0; kc < 8; ++kc)
            afr[g][kc] = *(const bf16x8*)(WA + (((wv * 4 + g) * 8 + kc) * 64 + lane) * 8);

    // bin populations -> SGPRs (uniform) + total unit count
    int ghs[16];
#pragma unroll
    for (int i = 0; i < 16; ++i)
        ghs[i] = __builtin_amdgcn_readfirstlane(gh[i]);
    int tot = 0;
#pragma unroll
    for (int i = 0; i < 16; ++i) tot += (ghs[i] + 31) >> 5;

    const int      rdo_b = lane31 * 256;           // byte offset of own h row
    const unsigned xv    = (unsigned)((lane31 & 7) << 4);
    const int      jbase = wv * 32 + 4 * hl;
    const int      ccb   = wv * 4 + hl * 2;        // chunk base (g adds g*16)
    int* const tick_p = (int*)&hbuf[0][0];         // ticket broadcast slot

    for (;;) {
        __syncthreads();               // prev unit's hbuf reads done
                                       // (iter 0: drains ptab staging)
        if (tid == 0) *tick_p = atomicAdd(gh + 16, 1);
        __syncthreads();               // ticket visible to all waves
        const int k = *tick_p;
        if (k >= tot) break;

        // map ticket -> (bin, widx): longest-first (b ascending), scalar
        int rem = k, bsel = 0, found = 0;
#pragma unroll
        for (int b2 = 0; b2 < 16; ++b2) {
            int nb = (ghs[b2] + 31) >> 5;
            if (!found) {
                if (rem < nb) { bsel = b2; found = 1; }
                else rem -= nb;
            }
        }
        const int widx = rem;
        const int cnt  = ghs[bsel];
        const int ml   = 16 - bsel;    // uniform trip count (>=1)

        // own seq id + packed words (8 bits each) in a 128-bit shift register
        const int slot = widx * WGSEQ + lane31;
        const int live = slot < cnt;
        const int sid  = live ? perm[bsel * BINCAP + slot] : 0;
        unsigned long long u0, u1;
        {
            const i32x4* wp = (const i32x4*)(word_ids + sid * SEQL);
            i32x4 a = wp[0], b4 = wp[1], c4 = wp[2], d4 = wp[3];
            unsigned lo0 = (unsigned)(a.x  | (a.y  << 8) | (a.z  << 16) | (a.w  << 24));
            unsigned hi0 = (unsigned)(b4.x | (b4.y << 8) | (b4.z << 16) | (b4.w << 24));
            unsigned lo1 = (unsigned)(c4.x | (c4.y << 8) | (c4.z << 16) | (c4.w << 24));
            unsigned hi1 = (unsigned)(d4.x | (d4.y << 8) | (d4.z << 16) | (d4.w << 24));
            u0 = ((unsigned long long)hi0 << 32) | lo0;
            u1 = ((unsigned long long)hi1 << 32) | lo1;
        }

        f32x4 cq[4] = {{0,0,0,0},{0,0,0,0},{0,0,0,0},{0,0,0,0}};

#pragma unroll 1
        for (int t = 0; t < ml; ++t) {
            const int w = (int)(u0 & 63);
            u0 = (u0 >> 8) | (u1 << 56); u1 >>= 8;

            // acc init = gate pre-activations P[w] from static LDS table
            AccU acc[4];
            {
                const char*    rowp = (const char*)ptab + (w << 10);
                const unsigned wx   = (unsigned)((w & 7) << 4);
#pragma unroll
                for (int g = 0; g < 4; ++g)
#pragma unroll
                    for (int s = 0; s < 2; ++s) {
                        const unsigned off =
                            ((unsigned)((g * 16 + ccb + s) << 4)) ^ wx;
                        f16x8 hv = *(const f16x8*)(rowp + off);
#pragma unroll
                        for (int kk = 0; kk < 8; ++kk)
                            acc[g].f[s * 8 + kk] = (float)hv[kk];
                    }
            }

            if (t > 0) {   // recurrent GEMM (t=0 has h=0)
                const char* hr = (const char*)hbuf[t & 1];
                bf16x8 bfv[8];
#pragma unroll
                for (int kc = 0; kc < 8; ++kc)
                    bfv[kc] = *(const bf16x8*)(hr + rdo_b +
                                  (((unsigned)(kc * 32 + hl * 16)) ^ xv));
#pragma unroll
                for (int kc = 0; kc < 8; ++kc) {
                    const bf16x8 bb = bfv[kc];
#pragma unroll
                    for (int g = 0; g < 4; ++g)
                        acc[g].v = __builtin_amdgcn_mfma_f32_32x32x16_bf16(
                            afr[g][kc], bb, acc[g].v, 0, 0, 0);
                }
            }

            const int wr = (t < ml - 1);
            char* hw = (char*)hbuf[(t + 1) & 1];
#pragma unroll
            for (int q = 0; q < 4; ++q) {
                float hv4[4];
#pragma unroll
                for (int d = 0; d < 4; ++d) {
                    const int r = q * 4 + d;
                    // single-rcp cell update (exact algebra):
                    // cn = (c*(1+ei)(1+eg) + (eg-1)(1+ef)) / ((1+ef)(1+ei)(1+eg))
                    float ei = __builtin_amdgcn_exp2f(acc[0].f[r] * -1.44269504f);
                    float ef = __builtin_amdgcn_exp2f(acc[1].f[r] * -1.44269504f);
                    float eg = __builtin_amdgcn_exp2f(acc[2].f[r] *  2.88539008f);
                    float ai = 1.f + ei, af = 1.f + ef, ag = 1.f + eg;
                    float t1 = ai * ag;
                    float R  = __builtin_amdgcn_rcpf(t1 * af);
                    float cn = __builtin_fmaf(cq[q][d], t1, (eg - 1.f) * af) * R;
                    cq[q][d] = cn;
                    if (wr) {
                        // h = sig(o)*tanh(cn) = (ec-1)/((1+eo)(1+ec))
                        float eo = __builtin_amdgcn_exp2f(acc[3].f[r] * -1.44269504f);
                        float ec = __builtin_amdgcn_exp2f(cn * 2.88539008f);
                        hv4[d] = (ec - 1.f) *
                                 __builtin_amdgcn_rcpf((1.f + eo) * (1.f + ec));
                    }
                }
                if (wr) {
                    unsigned int plo_, phi_;
                    asm("v_cvt_pk_bf16_f32 %0, %1, %2"
                        : "=v"(plo_) : "v"(hv4[0]), "v"(hv4[1]));
                    asm("v_cvt_pk_bf16_f32 %0, %1, %2"
                        : "=v"(phi_) : "v"(hv4[2]), "v"(hv4[3]));
                    unsigned long long pu_ =
                        ((unsigned long long)phi_ << 32) | plo_;
                    *(unsigned long long*)(hw + rdo_b +
                        (((unsigned)(wv * 64 + q * 16)) ^ xv) + hl * 8) = pu_;
                }
            }
            if (wr) __syncthreads();   // h(t+1) visible; single barrier/step
        }

        // final cell state -> original seq order (dwordx4 stores)
        if (live) {
#pragma unroll
            for (int q = 0; q < 4; ++q)
                *(f32x4*)(c_out + sid * HDIM + jbase + 8 * q) = cq[q];
        }
    }
}

// ---------------------------------------------------------------------------
// Per-batch epilogue: gram -> cosine -> conv1 -> conv2 -> scorer -> sigmoid.
// reps row stride 136 f32 -> gram-dot rows on bank offsets {0,8,16,24}
// (verified -4us on residue, R9).
// ---------------------------------------------------------------------------
__global__ __launch_bounds__(256) void epilogue(
    const float* __restrict__ c_ws,
    const float* __restrict__ conv1_w, const float* __restrict__ conv1_b,
    const float* __restrict__ conv2_w, const float* __restrict__ conv2_b,
    const float* __restrict__ scorer_w, const float* __restrict__ scorer_b,
    float* __restrict__ out)
{
    __shared__ __align__(16) float reps[8 * NWRD * RSTR];   // 17.4 KB
    __shared__ float gram_s[8 * 16];

    const int tid = threadIdx.x;
    const int b0  = blockIdx.x * 8;

    for (int i = tid; i < 8 * NWRD * HDIM; i += 256)
        reps[(i >> 7) * RSTR + (i & 127)] = c_ws[b0 * NWRD * HDIM + i];
    __syncthreads();

    const int bt  = tid >> 5;   // 0..7
    const int sub = tid & 31;

    float dval = 0.f;
    if (sub < 16) {
        int i = sub >> 2, j = sub & 3;
        const f32x4* ci = (const f32x4*)(reps + (bt * 4 + i) * RSTR);
        const f32x4* cj = (const f32x4*)(reps + (bt * 4 + j) * RSTR);
        f32x4 s4 = {0.f, 0.f, 0.f, 0.f};
        for (int k = 0; k < HDIM / 4; ++k) s4 += ci[k] * cj[k];
        dval = s4.x + s4.y + s4.z + s4.w;
        gram_s[bt * 16 + sub] = dval;
    }
    __syncthreads();
    float cosv = 0.f;
    if (sub < 16) {
        int i = sub >> 2, j = sub & 3;
        float di = gram_s[bt * 16 + i * 4 + i];
        float dj = gram_s[bt * 16 + j * 4 + j];
        cosv = __fdividef(dval, sqrtf(di * dj));
    }
    __syncthreads();
    if (sub < 16) gram_s[bt * 16 + sub] = cosv;
    __syncthreads();

    if (sub == 0) {
        float img[4][4];
#pragma unroll
        for (int i = 0; i < 4; ++i)
#pragma unroll
            for (int j = 0; j < 4; ++j) img[i][j] = gram_s[bt * 16 + i * 4 + j];

        float o1[4][3][3];
#pragma unroll
        for (int ch = 0; ch < 4; ++ch) {
            float w00 = conv1_w[ch*4+0], w01 = conv1_w[ch*4+1];
            float w10 = conv1_w[ch*4+2], w11 = conv1_w[ch*4+3];
            float bb  = conv1_b[ch];
#pragma unroll
            for (int y = 0; y < 3; ++y)
#pragma unroll
                for (int x = 0; x < 3; ++x) {
                    float s = bb + w00*img[y][x]   + w01*img[y][x+1]
                                 + w10*img[y+1][x] + w11*img[y+1][x+1];
                    o1[ch][y][x] = s > 0.f ? s : 0.f;
                }
        }
        float sc = scorer_b[0];
#pragma unroll
        for (int oc = 0; oc < 8; ++oc) {
            float bb = conv2_b[oc];
#pragma unroll
            for (int y = 0; y < 2; ++y)
#pragma unroll
                for (int x = 0; x < 2; ++x) {
                    float s = bb;
#pragma unroll
                    for (int ic = 0; ic < 4; ++ic) {
                        const float* w = conv2_w + oc * 16 + ic * 4;
                        s += w[0]*o1[ic][y][x]   + w[1]*o1[ic][y][x+1]
                           + w[2]*o1[ic][y+1][x] + w[3]*o1[ic][y+1][x+1];
                    }
                    float rl = s > 0.f ? s : 0.f;
                    sc += rl * scorer_w[oc * 4 + y * 2 + x];
                }
        }
        out[blockIdx.x * 8 + bt] = sigm(sc);
    }
}

extern "C" void kernel_launch(void* const* d_in, const int* in_sizes, int n_in,
                              void* d_out, int out_size, void* d_ws, size_t ws_size,
                              hipStream_t stream)
{
    const int*   word_ids = (const int*)d_in[0];
    const int*   lengths  = (const int*)d_in[1];
    const float* emb      = (const float*)d_in[2];
    const float* W_ih     = (const float*)d_in[3];
    const float* W_hh     = (const float*)d_in[4];
    const float* b_ih     = (const float*)d_in[5];
    const float* b_hh     = (const float*)d_in[6];
    const float* conv1_w  = (const float*)d_in[7];
    const float* conv1_b  = (const float*)d_in[8];
    const float* conv2_w  = (const float*)d_in[9];
    const float* conv2_b  = (const float*)d_in[10];
    const float* scorer_w = (const float*)d_in[11];
    const float* scorer_b = (const float*)d_in[12];
    float* out = (float*)d_out;

    // workspace layout
    char* ws = (char*)d_ws;
    unsigned short* P2H  = (unsigned short*)(ws + 0);         // 64 KB (f16 table)
    unsigned short* WA   = (unsigned short*)(ws + (128<<10)); // 128 KB
    int*            perm = (int*)(ws + (256<<10));            // 16*2560*4 = 160 KB
    int*            gh   = (int*)(ws + (416<<10));            // 16 cursors + ticket
    float*          c_ws = (float*)(ws + (512<<10));          // 16 MB

    hipMemsetAsync(gh, 0, 17 * sizeof(int), stream);
    prep4   <<<512,  256, 0, stream>>>(emb, W_ih, b_ih, b_hh, W_hh, lengths,
                                       P2H, WA, perm, gh);
    lstm4   <<<NBLK, 256, 0, stream>>>(word_ids, perm, gh, P2H, WA, c_ws);
    epilogue<<<BSZ / 8, 256, 0, stream>>>(c_ws, conv1_w, conv1_b, conv2_w, conv2_b,
                                          scorer_w, scorer_b, out);
}